// Round 10
// baseline (31.550 us; speedup 1.0000x reference)
//
#include <hip/hip_runtime.h>

#define B_DIM 8
#define T_DIM 16
#define H_IN 500
#define W_IN 500
#define HW (H_IN * W_IN)
#define NPH 127
#define NPW 127
#define LSTR 516      // 512+4 LDS row stride: transposed gathers stay ~2-way (free)
#define NT 512
#define BANDS 32      // 16-row bands per image
#define ROWS 16

typedef float f4 __attribute__((ext_vector_type(4)));

// One block per (b, q): owns output rows [16q, 16q+16), patches 4q..4q+3
// (R8 whole-line structure). R10: software pipeline — the band is computed in
// four 4-row chunks with double-buffered register prefetch; patch-store
// bursts are placed AFTER the next chunk's 16 global loads are issued (same
// barrier region), so store traffic executes while loads are in flight.
// No load is live across any barrier (avoids the vmcnt(0) barrier drain).
__global__ __launch_bounds__(NT) void k_band(const float* __restrict__ in,
                                             const float* __restrict__ wgt,
                                             float* __restrict__ patches,
                                             float* __restrict__ crop) {
    __shared__ float lds[ROWS * LSTR];
    __shared__ f4 wlds[T_DIM * 4];       // weight[t][r][0..3]
    int tid = threadIdx.x;
    if (tid < T_DIM * 4) wlds[tid] = reinterpret_cast<const f4*>(wgt)[tid];

    int orig = blockIdx.x;               // 256 blocks; b = orig&7 -> XCD-local image
    int b = orig & 7;
    int q = orig >> 3;                   // 0..31
    __syncthreads();

    int rc = tid >> 7;                   // row within chunk: 0..3
    int c  = (tid & 127) * 4;            // col 0..508
    bool cv = (c < W_IN);
    const float* ibase = in + (size_t)b * T_DIM * HW + c;

    f4 xA[T_DIM], xB[T_DIM];

    // ---- helpers ----
    auto issue = [&](int k, f4* xv) {
        int h = q * ROWS + k * 4 + rc;
        if (h < H_IN && cv) {
            const float* p = ibase + h * W_IN;
            #pragma unroll
            for (int t = 0; t < T_DIM; ++t)
                xv[t] = *reinterpret_cast<const f4*>(p + (size_t)t * HW);
        }
    };
    auto fma_store = [&](int k, f4* xv) {
        int r = k * 4 + rc;
        int h = q * ROWS + r;
        f4 acc = {0.f, 0.f, 0.f, 0.f};
        if (h < H_IN && cv) {
            int hr = h & 3;
            #pragma unroll
            for (int t = 0; t < T_DIM; ++t)
                acc += xv[t] * wlds[t * 4 + hr];
            *reinterpret_cast<f4*>(crop + ((size_t)b * H_IN + h) * W_IN + c) = acc;
        }
        *reinterpret_cast<f4*>(&lds[r * LSTR + c]) = acc;
    };
    f4* pbase = reinterpret_cast<f4*>(patches)
              + ((size_t)b * NPH + (size_t)4 * q) * NPW * 16;
    auto emit_full = [&](int sub) {      // patch 4q+sub from lds rows sub*4..sub*4+7
        f4* dst = pbase + (size_t)sub * NPW * 16;
        for (int e4 = tid; e4 < NPW * 16; e4 += NT) {
            int i0 = (e4 & 1) * 4;
            int j  = (e4 >> 1) & 7;
            int pw = e4 >> 4;
            int col = pw * 4 + j;
            int r0 = sub * 4 + i0;
            f4 v;
            v.x = lds[(r0 + 0) * LSTR + col];
            v.y = lds[(r0 + 1) * LSTR + col];
            v.z = lds[(r0 + 2) * LSTR + col];
            v.w = lds[(r0 + 3) * LSTR + col];
            dst[e4] = v;
        }
    };

    // ---- pipelined schedule ----
    issue(0, xA);
    issue(1, xB);
    fma_store(0, xA);                    // rows 0..3
    fma_store(1, xB);                    // rows 4..7
    __syncthreads();

    issue(2, xA);                        // loads in flight under P0 stores
    emit_full(0);                        // needs rows 0..7
    if (q > 0) {                         // half patch ph=4q-1, i=4..7 (rows 0..3)
        f4* dst = reinterpret_cast<f4*>(patches)
                + ((size_t)b * NPH + (size_t)(4 * q - 1)) * NPW * 16;
        for (int e = tid; e < NPW * 8; e += NT) {
            int j  = e & 7;
            int pw = e >> 3;
            int col = pw * 4 + j;
            f4 v;
            v.x = lds[0 * LSTR + col];
            v.y = lds[1 * LSTR + col];
            v.z = lds[2 * LSTR + col];
            v.w = lds[3 * LSTR + col];
            dst[pw * 16 + j * 2 + 1] = v;
        }
    }
    fma_store(2, xA);                    // rows 8..11
    __syncthreads();

    issue(3, xB);                        // loads in flight under P1 stores
    emit_full(1);                        // needs rows 4..11
    fma_store(3, xB);                    // rows 12..15
    __syncthreads();

    emit_full(2);                        // needs rows 8..15
    if (q < BANDS - 1) {                 // half patch ph=4q+3, i=0..3 (rows 12..15)
        f4* dst = pbase + (size_t)3 * NPW * 16;
        for (int e = tid; e < NPW * 8; e += NT) {
            int j  = e & 7;
            int pw = e >> 3;
            int col = pw * 4 + j;
            f4 v;
            v.x = lds[12 * LSTR + col];
            v.y = lds[13 * LSTR + col];
            v.z = lds[14 * LSTR + col];
            v.w = lds[15 * LSTR + col];
            dst[pw * 16 + j * 2] = v;
        }
    }
}

extern "C" void kernel_launch(void* const* d_in, const int* in_sizes, int n_in,
                              void* d_out, int out_size, void* d_ws, size_t ws_size,
                              hipStream_t stream) {
    const float* in  = (const float*)d_in[0];
    const float* wgt = (const float*)d_in[1];
    float* out     = (float*)d_out;
    float* patches = out;                                      // 8*16129*64 floats
    float* crop    = out + (size_t)B_DIM * NPH * NPW * 64;     // then 8*500*500

    k_band<<<B_DIM * BANDS, NT, 0, stream>>>(in, wgt, patches, crop);
}

// Round 11
// 30.935 us; speedup vs baseline: 1.0199x; 1.0199x over previous
//
#include <hip/hip_runtime.h>

#define B_DIM 8
#define T_DIM 16
#define H_IN 500
#define W_IN 500
#define NPH 127
#define NPW 127
#define LSTR 516      // 512+4 LDS row stride: transposed gathers stay ~2-way (free)
#define NT 512
#define BANDS 32      // 16-row bands per image
#define ROWS 16

typedef float f4 __attribute__((ext_vector_type(4)));

// R9 (best: 29.84 us = 5.67 TB/s effective, 90% of measured copy ceiling).
// One block per (b, q): owns output rows [16q, 16q+16). Patches 4q..4q+2 are
// fully block-local (whole-line writes); only ph=4q+3 (31 of 127) is
// cross-block interleaved. Phase A batches all 16 t-plane loads into
// registers before the FMA pass (~16 outstanding 16B loads/wave).
__global__ __launch_bounds__(NT) void k_band(const float* __restrict__ in,
                                             const float* __restrict__ wgt,
                                             float* __restrict__ patches,
                                             float* __restrict__ crop) {
    __shared__ float lds[ROWS * LSTR];
    __shared__ f4 wlds[T_DIM * 4];       // weight[t][r][0..3]
    int tid = threadIdx.x;
    if (tid < T_DIM * 4) wlds[tid] = reinterpret_cast<const f4*>(wgt)[tid];

    // b = orig&7: all 32 bands of one image on one XCD -> half-line partner
    // blocks (bands q, q+1) share that XCD's L2 for write merging.
    int orig = blockIdx.x;               // 256 blocks
    int b = orig & 7;
    int q = orig >> 3;                   // 0..31
    __syncthreads();

    // ---- Phase A: compute 16 rows x 512 cols into LDS (+ crop write) ----
    #pragma unroll
    for (int k = 0; k < 4; ++k) {
        int e = tid + k * NT;            // 0..2047 f4 slots
        int r = e >> 7;                  // band row 0..15
        int c = (e & 127) * 4;           // col 0..508
        int h = q * ROWS + r;
        f4 acc = {0.f, 0.f, 0.f, 0.f};
        if (h < H_IN && c < W_IN) {      // 500 % 4 == 0: group-exact
            const float* base = in + (size_t)b * T_DIM * (H_IN * W_IN) + h * W_IN + c;
            int hr = h & 3;
            f4 xv[T_DIM];
            #pragma unroll
            for (int t = 0; t < T_DIM; ++t)   // 16 loads issued back-to-back
                xv[t] = *reinterpret_cast<const f4*>(base + (size_t)t * (H_IN * W_IN));
            #pragma unroll
            for (int t = 0; t < T_DIM; ++t)   // then the FMA pass
                acc += xv[t] * wlds[t * 4 + hr];
            *reinterpret_cast<f4*>(crop + ((size_t)b * H_IN + h) * W_IN + c) = acc;
        }
        *reinterpret_cast<f4*>(&lds[r * LSTR + c]) = acc;
    }
    __syncthreads();

    // ---- Phase B: full patches 4q, 4q+1, 4q+2 (whole-line stores) ----
    f4* pbase = reinterpret_cast<f4*>(patches)
              + ((size_t)b * NPH + (size_t)4 * q) * NPW * 16;
    #pragma unroll
    for (int sub = 0; sub < 3; ++sub) {
        f4* dst = pbase + (size_t)sub * NPW * 16;
        for (int e4 = tid; e4 < NPW * 16; e4 += NT) {
            int i0 = (e4 & 1) * 4;
            int j  = (e4 >> 1) & 7;
            int pw = e4 >> 4;
            int col = pw * 4 + j;
            int r0 = sub * 4 + i0;       // rows sub*4 .. sub*4+7
            f4 v;
            v.x = lds[(r0 + 0) * LSTR + col];
            v.y = lds[(r0 + 1) * LSTR + col];
            v.z = lds[(r0 + 2) * LSTR + col];
            v.w = lds[(r0 + 3) * LSTR + col];
            dst[e4] = v;
        }
    }
    // ---- Half patch ph=4q+3, i=0..3 (own rows 12..15, even f4 slots) ----
    if (q < BANDS - 1) {
        f4* dst = pbase + (size_t)3 * NPW * 16;
        for (int e = tid; e < NPW * 8; e += NT) {
            int j  = e & 7;
            int pw = e >> 3;
            int col = pw * 4 + j;
            f4 v;
            v.x = lds[12 * LSTR + col];
            v.y = lds[13 * LSTR + col];
            v.z = lds[14 * LSTR + col];
            v.w = lds[15 * LSTR + col];
            dst[pw * 16 + j * 2] = v;
        }
    }
    // ---- Half patch ph=4q-1, i=4..7 (own rows 0..3, odd f4 slots) ----
    if (q > 0) {
        f4* dst = reinterpret_cast<f4*>(patches)
                + ((size_t)b * NPH + (size_t)(4 * q - 1)) * NPW * 16;
        for (int e = tid; e < NPW * 8; e += NT) {
            int j  = e & 7;
            int pw = e >> 3;
            int col = pw * 4 + j;
            f4 v;
            v.x = lds[0 * LSTR + col];
            v.y = lds[1 * LSTR + col];
            v.z = lds[2 * LSTR + col];
            v.w = lds[3 * LSTR + col];
            dst[pw * 16 + j * 2 + 1] = v;
        }
    }
}

extern "C" void kernel_launch(void* const* d_in, const int* in_sizes, int n_in,
                              void* d_out, int out_size, void* d_ws, size_t ws_size,
                              hipStream_t stream) {
    const float* in  = (const float*)d_in[0];
    const float* wgt = (const float*)d_in[1];
    float* out     = (float*)d_out;
    float* patches = out;                                      // 8*16129*64 floats
    float* crop    = out + (size_t)B_DIM * NPH * NPW * 64;     // then 8*500*500

    k_band<<<B_DIM * BANDS, NT, 0, stream>>>(in, wgt, patches, crop);
}